// Round 3
// baseline (593.054 us; speedup 1.0000x reference)
//
#include <hip/hip_runtime.h>
#include <stdint.h>

#define D_MODEL 1024
#define NHEADS 16
#define HDIM 64
#define CHUNK 2048
#define SEQ 8192
#define NCHUNK 4

typedef __attribute__((ext_vector_type(8))) short bf16x8;
typedef __attribute__((ext_vector_type(4))) float f32x4;

static __device__ __forceinline__ short f2bf(float f) {
    unsigned int u = __builtin_bit_cast(unsigned int, f);
    u = (u + 0x7FFFu + ((u >> 16) & 1u)) >> 16;
    return (short)u;
}

// pack two f32 -> two bf16 (round-half-up; cheap: 2 adds + perm)
static __device__ __forceinline__ unsigned int pkbf(float a, float b) {
    unsigned int ua = __builtin_bit_cast(unsigned int, a) + 0x8000u;
    unsigned int ub = __builtin_bit_cast(unsigned int, b) + 0x8000u;
    return (ua >> 16) | (ub & 0xFFFF0000u);
}

static __device__ __forceinline__ void gl_lds16(const void* g, void* l) {
    __builtin_amdgcn_global_load_lds((__attribute__((address_space(1))) void*)g,
                                     (__attribute__((address_space(3))) void*)l,
                                     16, 0, 0);
}

// ---------------- fp32 -> bf16 conversion ----------------
__global__ void cvt_f32_bf16(const float* __restrict__ in, short* __restrict__ out, int n) {
    int i = (blockIdx.x * 256 + threadIdx.x) * 4;
    if (i >= n) return;
    float4 v = *(const float4*)(in + i);
    short4 o;
    o.x = f2bf(v.x); o.y = f2bf(v.y); o.z = f2bf(v.z); o.w = f2bf(v.w);
    *(short4*)(out + i) = o;
}

// ---------------- bf16 GEMM: C[M,N] = A[M,K] * B[N,K]^T ----------------
template<bool OUT_BF16>
__global__ __launch_bounds__(256) void gemm_bt(const short* __restrict__ A,
                                               const short* __restrict__ B,
                                               void* __restrict__ Cout,
                                               int M, int N, int K) {
    __shared__ __align__(16) short As[128 * 32];
    __shared__ __align__(16) short Bs[128 * 32];
    const int tid  = threadIdx.x;
    const int lane = tid & 63;
    const int w    = tid >> 6;
    const int wr   = w >> 1, wc = w & 1;
    const int rowBase = blockIdx.y * 128;
    const int colBase = blockIdx.x * 128;
    const int quad = lane >> 4;
    const int cl   = lane & 15;

    f32x4 acc[4][4];
    #pragma unroll
    for (int i = 0; i < 4; ++i)
        #pragma unroll
        for (int j = 0; j < 4; ++j)
            acc[i][j] = (f32x4){0.f, 0.f, 0.f, 0.f};

    const int tr = tid >> 2;
    const int tc = (tid & 3) * 8;
    const short* gA0 = A + (size_t)(rowBase + tr) * K + tc;
    const short* gA1 = A + (size_t)(rowBase + 64 + tr) * K + tc;
    const short* gB0 = B + (size_t)(colBase + tr) * K + tc;
    const short* gB1 = B + (size_t)(colBase + 64 + tr) * K + tc;

    for (int k0 = 0; k0 < K; k0 += 32) {
        gl_lds16(gA0 + k0, &As[tid * 8]);
        gl_lds16(gA1 + k0, &As[2048 + tid * 8]);
        gl_lds16(gB0 + k0, &Bs[tid * 8]);
        gl_lds16(gB1 + k0, &Bs[2048 + tid * 8]);
        __syncthreads();

        bf16x8 af[4], bfr[4];
        #pragma unroll
        for (int mi = 0; mi < 4; ++mi)
            af[mi] = *(const bf16x8*)&As[(wr * 64 + mi * 16 + cl) * 32 + quad * 8];
        #pragma unroll
        for (int ni = 0; ni < 4; ++ni)
            bfr[ni] = *(const bf16x8*)&Bs[(wc * 64 + ni * 16 + cl) * 32 + quad * 8];

        #pragma unroll
        for (int mi = 0; mi < 4; ++mi)
            #pragma unroll
            for (int ni = 0; ni < 4; ++ni)
                acc[mi][ni] = __builtin_amdgcn_mfma_f32_16x16x32_bf16(af[mi], bfr[ni], acc[mi][ni], 0, 0, 0);
        __syncthreads();
    }

    #pragma unroll
    for (int mi = 0; mi < 4; ++mi)
        #pragma unroll
        for (int ni = 0; ni < 4; ++ni)
            #pragma unroll
            for (int r = 0; r < 4; ++r) {
                int row = rowBase + wr * 64 + mi * 16 + quad * 4 + r;
                int col = colBase + wc * 64 + ni * 16 + cl;
                if (OUT_BF16)
                    ((short*)Cout)[(size_t)row * N + col] = f2bf(acc[mi][ni][r]);
                else
                    ((float*)Cout)[(size_t)row * N + col] = acc[mi][ni][r];
            }
}

// ---------------- V transpose: V[seq][1024] -> VT[h][n][d][key] ----------------
__global__ __launch_bounds__(256) void transpose_v(const short* __restrict__ V,
                                                   short* __restrict__ VT) {
    __shared__ __align__(16) short Lt[64 * 64];
    const int tid = threadIdx.x;
    const int r0 = blockIdx.x * 64;
    const int c0 = blockIdx.y * 64;
    const int n = r0 >> 11;
    const int key0 = r0 & 2047;
    const int h = c0 >> 6;

    union { uint4 u; short s[8]; } v;
    #pragma unroll
    for (int i = 0; i < 2; ++i) {
        int rr = i * 32 + (tid >> 3);
        int c8 = tid & 7;
        v.u = *(const uint4*)(V + (size_t)(r0 + rr) * D_MODEL + c0 + c8 * 8);
        #pragma unroll
        for (int j = 0; j < 8; ++j) {
            int c = c8 * 8 + j;
            int slot = c * 8 + ((rr >> 3) ^ ((c >> 3) & 7));
            Lt[slot * 8 + (rr & 7)] = v.s[j];
        }
    }
    __syncthreads();
    #pragma unroll
    for (int i = 0; i < 2; ++i) {
        int dd = i * 32 + (tid >> 3);
        int k8 = tid & 7;
        int slot = dd * 8 + (k8 ^ ((dd >> 3) & 7));
        uint4 o = *(const uint4*)(Lt + slot * 8);
        *(uint4*)(VT + ((size_t)(h * NCHUNK + n) * HDIM + dd) * CHUNK + key0 + k8 * 8) = o;
    }
}

// ---------------- flash attention, chunk-local causal ----------------
// grid (16, NCHUNK, NHEADS); block 256 = 4 waves; block owns 128 q rows
// (qi swizzled for balance); 128-key tiles; key perm kappa = 8*cl + kt.
__global__ __launch_bounds__(256, 3) void attn_kernel(const short* __restrict__ Q,
                                                      const short* __restrict__ K,
                                                      const short* __restrict__ VT,
                                                      short* __restrict__ O) {
    __shared__ __align__(16) short Kt[8192];  // [row 0..127][chunk 0..7] slot=row*8+(c^((row>>3)&7))
    __shared__ __align__(16) short Vt[8192];  // [d 0..63][chunk 0..15]   slot=d*16+(c^(d&15))
    __shared__ __align__(16) short Pt[8192];  // per-wave 16x128 strip-P  slot=m*16+(c^m)
    const int tid  = threadIdx.x;
    const int lane = tid & 63;
    const int w    = tid >> 6;
    const int quad = lane >> 4;
    const int cl   = lane & 15;
    const int h = blockIdx.z;
    const int n = blockIdx.y;
    const int qi  = (blockIdx.x + blockIdx.y + blockIdx.z) & 15;  // load-balance swizzle
    const int qb0 = qi * 128;
    const int s0  = qb0 + w * 32;

    const short* Qg  = Q + (size_t)n * CHUNK * D_MODEL + h * HDIM;
    const short* Kg  = K + (size_t)n * CHUNK * D_MODEL + h * HDIM;
    const short* VTg = VT + (size_t)(h * NCHUNK + n) * HDIM * CHUNK;
    short* Pw = Pt + w * 2048;

    bf16x8 qf[2][2];
    #pragma unroll
    for (int st = 0; st < 2; ++st)
        #pragma unroll
        for (int hf = 0; hf < 2; ++hf)
            qf[st][hf] = *(const bf16x8*)(Qg + (size_t)(s0 + st * 16 + cl) * D_MODEL + hf * 32 + quad * 8);

    bf16x8 ones;
    #pragma unroll
    for (int i = 0; i < 8; ++i) ones[i] = (short)0x3F80;  // bf16 1.0

    f32x4 m4[2], l4[2], o_acc[2][4];
    #pragma unroll
    for (int st = 0; st < 2; ++st) {
        m4[st] = (f32x4){-3.0e38f, -3.0e38f, -3.0e38f, -3.0e38f};
        l4[st] = (f32x4){0.f, 0.f, 0.f, 0.f};
        #pragma unroll
        for (int dt = 0; dt < 4; ++dt) o_acc[st][dt] = (f32x4){0.f, 0.f, 0.f, 0.f};
    }

    const float cs = 0.18033688011f;  // log2(e)/sqrt(64)
    const int ntiles = qi + 1;

    for (int t = 0; t < ntiles; ++t) {
        const int kb = t * 128;
        __syncthreads();  // all waves done reading prev tile
        #pragma unroll
        for (int j = 0; j < 4; ++j) {
            int s = j * 256 + tid;
            int row = s >> 3;
            int c = (s & 7) ^ ((row >> 3) & 7);
            gl_lds16(Kg + (size_t)(kb + row) * D_MODEL + c * 8, Kt + s * 8);
        }
        #pragma unroll
        for (int j = 0; j < 4; ++j) {
            int s = j * 256 + tid;
            int d = s >> 4;
            int c = (s & 15) ^ (d & 15);
            gl_lds16(VTg + (size_t)d * CHUNK + kb + c * 8, Vt + s * 8);
        }
        __syncthreads();  // staged data visible (vmcnt drained)

        const bool full = (t < qi);  // only the last tile is diagonal/masked

        bf16x8 kf[8][2];
        #pragma unroll
        for (int kt = 0; kt < 8; ++kt)
            #pragma unroll
            for (int hf = 0; hf < 2; ++hf) {
                int row = 8 * cl + kt;
                int slot = row * 8 + ((hf * 4 + quad) ^ (cl & 7));
                kf[kt][hf] = *(const bf16x8*)(Kt + slot * 8);
            }

        #pragma unroll
        for (int st = 0; st < 2; ++st) {
            const int sb = s0 + st * 16;
            // ---- S = Q K^T (keys permuted: col (kt,cl) = key 8*cl+kt) ----
            f32x4 sa[8];
            #pragma unroll
            for (int kt = 0; kt < 8; ++kt) {
                sa[kt] = (f32x4){0.f, 0.f, 0.f, 0.f};
                sa[kt] = __builtin_amdgcn_mfma_f32_16x16x32_bf16(qf[st][0], kf[kt][0], sa[kt], 0, 0, 0);
                sa[kt] = __builtin_amdgcn_mfma_f32_16x16x32_bf16(qf[st][1], kf[kt][1], sa[kt], 0, 0, 0);
            }
            if (!full) {
                int k8 = kb + 8 * cl;
                #pragma unroll
                for (int r = 0; r < 4; ++r) {
                    int q = sb + quad * 4 + r;
                    #pragma unroll
                    for (int kt = 0; kt < 8; ++kt)
                        if (k8 + kt > q) sa[kt][r] = -3.0e38f;
                }
            }
            // ---- online softmax ----
            f32x4 mx = sa[0];
            #pragma unroll
            for (int kt = 1; kt < 8; ++kt)
                #pragma unroll
                for (int r = 0; r < 4; ++r) mx[r] = fmaxf(mx[r], sa[kt][r]);
            #pragma unroll
            for (int r = 0; r < 4; ++r) {
                float m = mx[r];
                m = fmaxf(m, __shfl_xor(m, 1));
                m = fmaxf(m, __shfl_xor(m, 2));
                m = fmaxf(m, __shfl_xor(m, 4));
                m = fmaxf(m, __shfl_xor(m, 8));
                mx[r] = m;
            }
            f32x4 alpha, nm;
            #pragma unroll
            for (int r = 0; r < 4; ++r) {
                float mnew = fmaxf(m4[st][r], mx[r]);
                alpha[r] = __builtin_amdgcn_exp2f((m4[st][r] - mnew) * cs);
                nm[r] = mnew * cs;
                m4[st][r] = mnew;
            }
            #pragma unroll
            for (int r = 0; r < 4; ++r) l4[st][r] *= alpha[r];
            #pragma unroll
            for (int dt = 0; dt < 4; ++dt)
                #pragma unroll
                for (int r = 0; r < 4; ++r) o_acc[st][dt][r] *= alpha[r];
            // p = exp2(s*cs - nm), packed write: row m holds keys 8cl..8cl+7
            #pragma unroll
            for (int r = 0; r < 4; ++r) {
                float p0 = __builtin_amdgcn_exp2f(__builtin_fmaf(sa[0][r], cs, -nm[r]));
                float p1 = __builtin_amdgcn_exp2f(__builtin_fmaf(sa[1][r], cs, -nm[r]));
                float p2 = __builtin_amdgcn_exp2f(__builtin_fmaf(sa[2][r], cs, -nm[r]));
                float p3 = __builtin_amdgcn_exp2f(__builtin_fmaf(sa[3][r], cs, -nm[r]));
                float p4 = __builtin_amdgcn_exp2f(__builtin_fmaf(sa[4][r], cs, -nm[r]));
                float p5 = __builtin_amdgcn_exp2f(__builtin_fmaf(sa[5][r], cs, -nm[r]));
                float p6 = __builtin_amdgcn_exp2f(__builtin_fmaf(sa[6][r], cs, -nm[r]));
                float p7 = __builtin_amdgcn_exp2f(__builtin_fmaf(sa[7][r], cs, -nm[r]));
                uint4 pk;
                pk.x = pkbf(p0, p1);
                pk.y = pkbf(p2, p3);
                pk.z = pkbf(p4, p5);
                pk.w = pkbf(p6, p7);
                int m = quad * 4 + r;
                *(uint4*)(Pw + (m * 16 + (cl ^ m)) * 8) = pk;
            }
            // ---- O += P V ; l += rowsum(P) via MFMA with ones ----
            bf16x8 pf[4];
            #pragma unroll
            for (int kc = 0; kc < 4; ++kc)
                pf[kc] = *(const bf16x8*)(Pw + (cl * 16 + ((kc * 4 + quad) ^ cl)) * 8);
            f32x4 rs = (f32x4){0.f, 0.f, 0.f, 0.f};
            #pragma unroll
            for (int kc = 0; kc < 4; ++kc)
                rs = __builtin_amdgcn_mfma_f32_16x16x32_bf16(pf[kc], ones, rs, 0, 0, 0);
            #pragma unroll
            for (int r = 0; r < 4; ++r) l4[st][r] += rs[r];
            #pragma unroll
            for (int dt = 0; dt < 4; ++dt) {
                #pragma unroll
                for (int kc = 0; kc < 4; ++kc) {
                    int d = dt * 16 + cl;
                    int slot = d * 16 + ((kc * 4 + quad) ^ (d & 15));
                    bf16x8 vf = *(const bf16x8*)(Vt + slot * 8);
                    o_acc[st][dt] = __builtin_amdgcn_mfma_f32_16x16x32_bf16(pf[kc], vf, o_acc[st][dt], 0, 0, 0);
                }
            }
        }
    }

    // epilogue: O/l -> bf16 store
    #pragma unroll
    for (int st = 0; st < 2; ++st) {
        f32x4 linv;
        #pragma unroll
        for (int r = 0; r < 4; ++r) linv[r] = __builtin_amdgcn_rcpf(l4[st][r]);
        #pragma unroll
        for (int dt = 0; dt < 4; ++dt)
            #pragma unroll
            for (int r = 0; r < 4; ++r) {
                float val = o_acc[st][dt][r] * linv[r];
                size_t row = (size_t)n * CHUNK + s0 + st * 16 + quad * 4 + r;
                O[row * D_MODEL + h * HDIM + dt * 16 + cl] = f2bf(val);
            }
    }
}

extern "C" void kernel_launch(void* const* d_in, const int* in_sizes, int n_in,
                              void* d_out, int out_size, void* d_ws, size_t ws_size,
                              hipStream_t stream) {
    const float* hs = (const float*)d_in[0];
    const float* Wq = (const float*)d_in[1];
    const float* Wk = (const float*)d_in[2];
    const float* Wv = (const float*)d_in[3];
    const float* Wo = (const float*)d_in[4];
    float* out = (float*)d_out;

    char* ws = (char*)d_ws;
    const size_t SZ_X = (size_t)SEQ * D_MODEL * sizeof(short);
    const size_t SZ_W = (size_t)D_MODEL * D_MODEL * sizeof(short);
    short* Xbf = (short*)(ws);
    short* Qbf = (short*)(ws + SZ_X);
    short* Kbf = (short*)(ws + 2 * SZ_X);
    short* Vbf = (short*)(ws + 3 * SZ_X);
    short* Abf = (short*)(ws + 4 * SZ_X);
    short* Wqb = (short*)(ws + 5 * SZ_X);
    short* Wkb = (short*)(ws + 5 * SZ_X + SZ_W);
    short* Wvb = (short*)(ws + 5 * SZ_X + 2 * SZ_W);
    short* Wob = (short*)(ws + 5 * SZ_X + 3 * SZ_W);
    short* VT  = Xbf;  // X dead after QKV GEMMs

    const int nHS = SEQ * D_MODEL;
    const int nW  = D_MODEL * D_MODEL;
    cvt_f32_bf16<<<nHS / 1024, 256, 0, stream>>>(hs, Xbf, nHS);
    cvt_f32_bf16<<<nW / 1024, 256, 0, stream>>>(Wq, Wqb, nW);
    cvt_f32_bf16<<<nW / 1024, 256, 0, stream>>>(Wk, Wkb, nW);
    cvt_f32_bf16<<<nW / 1024, 256, 0, stream>>>(Wv, Wvb, nW);
    cvt_f32_bf16<<<nW / 1024, 256, 0, stream>>>(Wo, Wob, nW);

    dim3 gg(D_MODEL / 128, SEQ / 128);
    gemm_bt<true><<<gg, 256, 0, stream>>>(Xbf, Wqb, Qbf, SEQ, D_MODEL, D_MODEL);
    gemm_bt<true><<<gg, 256, 0, stream>>>(Xbf, Wkb, Kbf, SEQ, D_MODEL, D_MODEL);
    gemm_bt<true><<<gg, 256, 0, stream>>>(Xbf, Wvb, Vbf, SEQ, D_MODEL, D_MODEL);

    transpose_v<<<dim3(SEQ / 64, D_MODEL / 64), 256, 0, stream>>>(Vbf, VT);

    attn_kernel<<<dim3(16, NCHUNK, NHEADS), 256, 0, stream>>>(Qbf, Kbf, VT, Abf);

    gemm_bt<false><<<gg, 256, 0, stream>>>(Abf, Wob, out, SEQ, D_MODEL, D_MODEL);
}

// Round 4
// 349.406 us; speedup vs baseline: 1.6973x; 1.6973x over previous
//
#include <hip/hip_runtime.h>
#include <stdint.h>

#define D_MODEL 1024
#define NHEADS 16
#define HDIM 64
#define CHUNK 2048
#define SEQ 8192
#define NCHUNK 4

typedef __attribute__((ext_vector_type(8))) short bf16x8;
typedef __attribute__((ext_vector_type(4))) float f32x4;

static __device__ __forceinline__ short f2bf(float f) {
    unsigned int u = __builtin_bit_cast(unsigned int, f);
    u = (u + 0x7FFFu + ((u >> 16) & 1u)) >> 16;
    return (short)u;
}

// pack two f32 -> two bf16 (round-half-up; cheap: 2 adds + perm)
static __device__ __forceinline__ unsigned int pkbf(float a, float b) {
    unsigned int ua = __builtin_bit_cast(unsigned int, a) + 0x8000u;
    unsigned int ub = __builtin_bit_cast(unsigned int, b) + 0x8000u;
    return (ua >> 16) | (ub & 0xFFFF0000u);
}

static __device__ __forceinline__ void gl_lds16(const void* g, void* l) {
    __builtin_amdgcn_global_load_lds((__attribute__((address_space(1))) void*)g,
                                     (__attribute__((address_space(3))) void*)l,
                                     16, 0, 0);
}

// ---------------- fp32 -> bf16 conversion ----------------
__global__ void cvt_f32_bf16(const float* __restrict__ in, short* __restrict__ out, int n) {
    int i = (blockIdx.x * 256 + threadIdx.x) * 4;
    if (i >= n) return;
    float4 v = *(const float4*)(in + i);
    short4 o;
    o.x = f2bf(v.x); o.y = f2bf(v.y); o.z = f2bf(v.z); o.w = f2bf(v.w);
    *(short4*)(out + i) = o;
}

// ---------------- bf16 GEMM: C[M,N] = A[M,K] * B[N,K]^T ----------------
template<bool OUT_BF16>
__global__ __launch_bounds__(256) void gemm_bt(const short* __restrict__ A,
                                               const short* __restrict__ B,
                                               void* __restrict__ Cout,
                                               int M, int N, int K) {
    __shared__ __align__(16) short As[128 * 32];
    __shared__ __align__(16) short Bs[128 * 32];
    const int tid  = threadIdx.x;
    const int lane = tid & 63;
    const int w    = tid >> 6;
    const int wr   = w >> 1, wc = w & 1;
    const int rowBase = blockIdx.y * 128;
    const int colBase = blockIdx.x * 128;
    const int quad = lane >> 4;
    const int cl   = lane & 15;

    f32x4 acc[4][4];
    #pragma unroll
    for (int i = 0; i < 4; ++i)
        #pragma unroll
        for (int j = 0; j < 4; ++j)
            acc[i][j] = (f32x4){0.f, 0.f, 0.f, 0.f};

    const int tr = tid >> 2;
    const int tc = (tid & 3) * 8;
    const short* gA0 = A + (size_t)(rowBase + tr) * K + tc;
    const short* gA1 = A + (size_t)(rowBase + 64 + tr) * K + tc;
    const short* gB0 = B + (size_t)(colBase + tr) * K + tc;
    const short* gB1 = B + (size_t)(colBase + 64 + tr) * K + tc;

    for (int k0 = 0; k0 < K; k0 += 32) {
        gl_lds16(gA0 + k0, &As[tid * 8]);
        gl_lds16(gA1 + k0, &As[2048 + tid * 8]);
        gl_lds16(gB0 + k0, &Bs[tid * 8]);
        gl_lds16(gB1 + k0, &Bs[2048 + tid * 8]);
        __syncthreads();

        bf16x8 af[4], bfr[4];
        #pragma unroll
        for (int mi = 0; mi < 4; ++mi)
            af[mi] = *(const bf16x8*)&As[(wr * 64 + mi * 16 + cl) * 32 + quad * 8];
        #pragma unroll
        for (int ni = 0; ni < 4; ++ni)
            bfr[ni] = *(const bf16x8*)&Bs[(wc * 64 + ni * 16 + cl) * 32 + quad * 8];

        #pragma unroll
        for (int mi = 0; mi < 4; ++mi)
            #pragma unroll
            for (int ni = 0; ni < 4; ++ni)
                acc[mi][ni] = __builtin_amdgcn_mfma_f32_16x16x32_bf16(af[mi], bfr[ni], acc[mi][ni], 0, 0, 0);
        __syncthreads();
    }

    #pragma unroll
    for (int mi = 0; mi < 4; ++mi)
        #pragma unroll
        for (int ni = 0; ni < 4; ++ni)
            #pragma unroll
            for (int r = 0; r < 4; ++r) {
                int row = rowBase + wr * 64 + mi * 16 + quad * 4 + r;
                int col = colBase + wc * 64 + ni * 16 + cl;
                if (OUT_BF16)
                    ((short*)Cout)[(size_t)row * N + col] = f2bf(acc[mi][ni][r]);
                else
                    ((float*)Cout)[(size_t)row * N + col] = acc[mi][ni][r];
            }
}

// ---------------- V transpose: V[seq][1024] -> VT[h][n][d][key] ----------------
__global__ __launch_bounds__(256) void transpose_v(const short* __restrict__ V,
                                                   short* __restrict__ VT) {
    __shared__ __align__(16) short Lt[64 * 64];
    const int tid = threadIdx.x;
    const int r0 = blockIdx.x * 64;
    const int c0 = blockIdx.y * 64;
    const int n = r0 >> 11;
    const int key0 = r0 & 2047;
    const int h = c0 >> 6;

    union { uint4 u; short s[8]; } v;
    #pragma unroll
    for (int i = 0; i < 2; ++i) {
        int rr = i * 32 + (tid >> 3);
        int c8 = tid & 7;
        v.u = *(const uint4*)(V + (size_t)(r0 + rr) * D_MODEL + c0 + c8 * 8);
        #pragma unroll
        for (int j = 0; j < 8; ++j) {
            int c = c8 * 8 + j;
            int slot = c * 8 + ((rr >> 3) ^ ((c >> 3) & 7));
            Lt[slot * 8 + (rr & 7)] = v.s[j];
        }
    }
    __syncthreads();
    #pragma unroll
    for (int i = 0; i < 2; ++i) {
        int dd = i * 32 + (tid >> 3);
        int k8 = tid & 7;
        int slot = dd * 8 + (k8 ^ ((dd >> 3) & 7));
        uint4 o = *(const uint4*)(Lt + slot * 8);
        *(uint4*)(VT + ((size_t)(h * NCHUNK + n) * HDIM + dd) * CHUNK + key0 + k8 * 8) = o;
    }
}

// ---------------- flash attention, chunk-local causal ----------------
// grid (16, NCHUNK, NHEADS); block 256 = 4 waves; block owns 128 q rows
// (qi swizzled for balance); 128-key tiles; key perm kappa = 8*cl + kt.
// K-fragments streamed from LDS inside the kt loop (NOT held live) to keep
// VGPR pressure ~140 — launch_bounds(256,3) caused catastrophic spills (R3).
__global__ __launch_bounds__(256, 2) void attn_kernel(const short* __restrict__ Q,
                                                      const short* __restrict__ K,
                                                      const short* __restrict__ VT,
                                                      short* __restrict__ O) {
    __shared__ __align__(16) short Kt[8192];  // [row 0..127][chunk 0..7] slot=row*8+(c^((row>>3)&7))
    __shared__ __align__(16) short Vt[8192];  // [d 0..63][chunk 0..15]   slot=d*16+(c^(d&15))
    __shared__ __align__(16) short Pt[8192];  // per-wave 16x128 strip-P  slot=m*16+(c^m)
    const int tid  = threadIdx.x;
    const int lane = tid & 63;
    const int w    = tid >> 6;
    const int quad = lane >> 4;
    const int cl   = lane & 15;
    const int h = blockIdx.z;
    const int n = blockIdx.y;
    const int qi  = (blockIdx.x + blockIdx.y + blockIdx.z) & 15;  // load-balance swizzle
    const int qb0 = qi * 128;
    const int s0  = qb0 + w * 32;

    const short* Qg  = Q + (size_t)n * CHUNK * D_MODEL + h * HDIM;
    const short* Kg  = K + (size_t)n * CHUNK * D_MODEL + h * HDIM;
    const short* VTg = VT + (size_t)(h * NCHUNK + n) * HDIM * CHUNK;
    short* Pw = Pt + w * 2048;

    bf16x8 qf[2][2];
    #pragma unroll
    for (int st = 0; st < 2; ++st)
        #pragma unroll
        for (int hf = 0; hf < 2; ++hf)
            qf[st][hf] = *(const bf16x8*)(Qg + (size_t)(s0 + st * 16 + cl) * D_MODEL + hf * 32 + quad * 8);

    bf16x8 ones;
    #pragma unroll
    for (int i = 0; i < 8; ++i) ones[i] = (short)0x3F80;  // bf16 1.0

    f32x4 m4[2], l4[2], o_acc[2][4];
    #pragma unroll
    for (int st = 0; st < 2; ++st) {
        m4[st] = (f32x4){-3.0e38f, -3.0e38f, -3.0e38f, -3.0e38f};
        l4[st] = (f32x4){0.f, 0.f, 0.f, 0.f};
        #pragma unroll
        for (int dt = 0; dt < 4; ++dt) o_acc[st][dt] = (f32x4){0.f, 0.f, 0.f, 0.f};
    }

    const float cs = 0.18033688011f;  // log2(e)/sqrt(64)
    const int ntiles = qi + 1;

    for (int t = 0; t < ntiles; ++t) {
        const int kb = t * 128;
        __syncthreads();  // all waves done reading prev tile
        #pragma unroll
        for (int j = 0; j < 4; ++j) {
            int s = j * 256 + tid;
            int row = s >> 3;
            int c = (s & 7) ^ ((row >> 3) & 7);
            gl_lds16(Kg + (size_t)(kb + row) * D_MODEL + c * 8, Kt + s * 8);
        }
        #pragma unroll
        for (int j = 0; j < 4; ++j) {
            int s = j * 256 + tid;
            int d = s >> 4;
            int c = (s & 15) ^ (d & 15);
            gl_lds16(VTg + (size_t)d * CHUNK + kb + c * 8, Vt + s * 8);
        }
        __syncthreads();  // staged data visible (vmcnt drained)

        const bool full = (t < qi);  // only the last tile is diagonal/masked

        #pragma unroll
        for (int st = 0; st < 2; ++st) {
            const int sb = s0 + st * 16;
            // ---- S = Q K^T (keys permuted: col (kt,cl) = key 8*cl+kt) ----
            // K fragments streamed per-kt (register pressure; see header note)
            f32x4 sa[8];
            #pragma unroll
            for (int kt = 0; kt < 8; ++kt) {
                int row = 8 * cl + kt;
                bf16x8 k0 = *(const bf16x8*)(Kt + (row * 8 + (quad ^ (cl & 7))) * 8);
                bf16x8 k1 = *(const bf16x8*)(Kt + (row * 8 + ((4 + quad) ^ (cl & 7))) * 8);
                sa[kt] = (f32x4){0.f, 0.f, 0.f, 0.f};
                sa[kt] = __builtin_amdgcn_mfma_f32_16x16x32_bf16(qf[st][0], k0, sa[kt], 0, 0, 0);
                sa[kt] = __builtin_amdgcn_mfma_f32_16x16x32_bf16(qf[st][1], k1, sa[kt], 0, 0, 0);
            }
            if (!full) {
                int k8 = kb + 8 * cl;
                #pragma unroll
                for (int r = 0; r < 4; ++r) {
                    int q = sb + quad * 4 + r;
                    #pragma unroll
                    for (int kt = 0; kt < 8; ++kt)
                        if (k8 + kt > q) sa[kt][r] = -3.0e38f;
                }
            }
            // ---- online softmax ----
            f32x4 mx = sa[0];
            #pragma unroll
            for (int kt = 1; kt < 8; ++kt)
                #pragma unroll
                for (int r = 0; r < 4; ++r) mx[r] = fmaxf(mx[r], sa[kt][r]);
            #pragma unroll
            for (int r = 0; r < 4; ++r) {
                float m = mx[r];
                m = fmaxf(m, __shfl_xor(m, 1));
                m = fmaxf(m, __shfl_xor(m, 2));
                m = fmaxf(m, __shfl_xor(m, 4));
                m = fmaxf(m, __shfl_xor(m, 8));
                mx[r] = m;
            }
            f32x4 alpha, nm;
            #pragma unroll
            for (int r = 0; r < 4; ++r) {
                float mnew = fmaxf(m4[st][r], mx[r]);
                alpha[r] = __builtin_amdgcn_exp2f((m4[st][r] - mnew) * cs);
                nm[r] = mnew * cs;
                m4[st][r] = mnew;
            }
            #pragma unroll
            for (int r = 0; r < 4; ++r) l4[st][r] *= alpha[r];
            #pragma unroll
            for (int dt = 0; dt < 4; ++dt)
                #pragma unroll
                for (int r = 0; r < 4; ++r) o_acc[st][dt][r] *= alpha[r];
            // p = exp2(s*cs - nm), packed write: row m holds keys 8cl..8cl+7
            #pragma unroll
            for (int r = 0; r < 4; ++r) {
                float p0 = __builtin_amdgcn_exp2f(__builtin_fmaf(sa[0][r], cs, -nm[r]));
                float p1 = __builtin_amdgcn_exp2f(__builtin_fmaf(sa[1][r], cs, -nm[r]));
                float p2 = __builtin_amdgcn_exp2f(__builtin_fmaf(sa[2][r], cs, -nm[r]));
                float p3 = __builtin_amdgcn_exp2f(__builtin_fmaf(sa[3][r], cs, -nm[r]));
                float p4 = __builtin_amdgcn_exp2f(__builtin_fmaf(sa[4][r], cs, -nm[r]));
                float p5 = __builtin_amdgcn_exp2f(__builtin_fmaf(sa[5][r], cs, -nm[r]));
                float p6 = __builtin_amdgcn_exp2f(__builtin_fmaf(sa[6][r], cs, -nm[r]));
                float p7 = __builtin_amdgcn_exp2f(__builtin_fmaf(sa[7][r], cs, -nm[r]));
                uint4 pk;
                pk.x = pkbf(p0, p1);
                pk.y = pkbf(p2, p3);
                pk.z = pkbf(p4, p5);
                pk.w = pkbf(p6, p7);
                int m = quad * 4 + r;
                *(uint4*)(Pw + (m * 16 + (cl ^ m)) * 8) = pk;
            }
            // ---- O += P V ; l += rowsum(P) via MFMA with ones ----
            bf16x8 pf[4];
            #pragma unroll
            for (int kc = 0; kc < 4; ++kc)
                pf[kc] = *(const bf16x8*)(Pw + (cl * 16 + ((kc * 4 + quad) ^ cl)) * 8);
            f32x4 rs = (f32x4){0.f, 0.f, 0.f, 0.f};
            #pragma unroll
            for (int kc = 0; kc < 4; ++kc)
                rs = __builtin_amdgcn_mfma_f32_16x16x32_bf16(pf[kc], ones, rs, 0, 0, 0);
            #pragma unroll
            for (int r = 0; r < 4; ++r) l4[st][r] += rs[r];
            #pragma unroll
            for (int dt = 0; dt < 4; ++dt) {
                #pragma unroll
                for (int kc = 0; kc < 4; ++kc) {
                    int d = dt * 16 + cl;
                    int slot = d * 16 + ((kc * 4 + quad) ^ (d & 15));
                    bf16x8 vf = *(const bf16x8*)(Vt + slot * 8);
                    o_acc[st][dt] = __builtin_amdgcn_mfma_f32_16x16x32_bf16(pf[kc], vf, o_acc[st][dt], 0, 0, 0);
                }
            }
        }
    }

    // epilogue: O/l -> bf16 store
    #pragma unroll
    for (int st = 0; st < 2; ++st) {
        f32x4 linv;
        #pragma unroll
        for (int r = 0; r < 4; ++r) linv[r] = __builtin_amdgcn_rcpf(l4[st][r]);
        #pragma unroll
        for (int dt = 0; dt < 4; ++dt)
            #pragma unroll
            for (int r = 0; r < 4; ++r) {
                float val = o_acc[st][dt][r] * linv[r];
                size_t row = (size_t)n * CHUNK + s0 + st * 16 + quad * 4 + r;
                O[row * D_MODEL + h * HDIM + dt * 16 + cl] = f2bf(val);
            }
    }
}

extern "C" void kernel_launch(void* const* d_in, const int* in_sizes, int n_in,
                              void* d_out, int out_size, void* d_ws, size_t ws_size,
                              hipStream_t stream) {
    const float* hs = (const float*)d_in[0];
    const float* Wq = (const float*)d_in[1];
    const float* Wk = (const float*)d_in[2];
    const float* Wv = (const float*)d_in[3];
    const float* Wo = (const float*)d_in[4];
    float* out = (float*)d_out;

    char* ws = (char*)d_ws;
    const size_t SZ_X = (size_t)SEQ * D_MODEL * sizeof(short);
    const size_t SZ_W = (size_t)D_MODEL * D_MODEL * sizeof(short);
    short* Xbf = (short*)(ws);
    short* Qbf = (short*)(ws + SZ_X);
    short* Kbf = (short*)(ws + 2 * SZ_X);
    short* Vbf = (short*)(ws + 3 * SZ_X);
    short* Abf = (short*)(ws + 4 * SZ_X);
    short* Wqb = (short*)(ws + 5 * SZ_X);
    short* Wkb = (short*)(ws + 5 * SZ_X + SZ_W);
    short* Wvb = (short*)(ws + 5 * SZ_X + 2 * SZ_W);
    short* Wob = (short*)(ws + 5 * SZ_X + 3 * SZ_W);
    short* VT  = Xbf;  // X dead after QKV GEMMs

    const int nHS = SEQ * D_MODEL;
    const int nW  = D_MODEL * D_MODEL;
    cvt_f32_bf16<<<nHS / 1024, 256, 0, stream>>>(hs, Xbf, nHS);
    cvt_f32_bf16<<<nW / 1024, 256, 0, stream>>>(Wq, Wqb, nW);
    cvt_f32_bf16<<<nW / 1024, 256, 0, stream>>>(Wk, Wkb, nW);
    cvt_f32_bf16<<<nW / 1024, 256, 0, stream>>>(Wv, Wvb, nW);
    cvt_f32_bf16<<<nW / 1024, 256, 0, stream>>>(Wo, Wob, nW);

    dim3 gg(D_MODEL / 128, SEQ / 128);
    gemm_bt<true><<<gg, 256, 0, stream>>>(Xbf, Wqb, Qbf, SEQ, D_MODEL, D_MODEL);
    gemm_bt<true><<<gg, 256, 0, stream>>>(Xbf, Wkb, Kbf, SEQ, D_MODEL, D_MODEL);
    gemm_bt<true><<<gg, 256, 0, stream>>>(Xbf, Wvb, Vbf, SEQ, D_MODEL, D_MODEL);

    transpose_v<<<dim3(SEQ / 64, D_MODEL / 64), 256, 0, stream>>>(Vbf, VT);

    attn_kernel<<<dim3(16, NCHUNK, NHEADS), 256, 0, stream>>>(Qbf, Kbf, VT, Abf);

    gemm_bt<false><<<gg, 256, 0, stream>>>(Abf, Wob, out, SEQ, D_MODEL, D_MODEL);
}